// Round 1
// baseline (298.126 us; speedup 1.0000x reference)
//
#include <hip/hip_runtime.h>
#include <stdint.h>

typedef unsigned short u16;
typedef __attribute__((ext_vector_type(8))) __bf16 bf16x8;
typedef __attribute__((ext_vector_type(4))) float f32x4;

__device__ __forceinline__ u16 f2bf(float f) {
  unsigned u = __float_as_uint(f);
  u += 0x7FFF + ((u >> 16) & 1);   // RNE
  return (u16)(u >> 16);
}

__device__ __forceinline__ float bf2f(u16 h) {
  return __uint_as_float(((unsigned)h) << 16);
}

__device__ __forceinline__ void llds16(const u16* g, u16* l) {
  __builtin_amdgcn_global_load_lds(
      (const __attribute__((address_space(1))) void*)g,
      (__attribute__((address_space(3))) void*)l, 16, 0, 0);
}

// ---------------------------------------------------------------------------
// cast fp32 -> bf16, 4 elems/thread
// ---------------------------------------------------------------------------
__global__ __launch_bounds__(256) void cast_f32_bf16(
    const float* __restrict__ in, u16* __restrict__ out, int n4) {
  int i = blockIdx.x * 256 + threadIdx.x;
  if (i >= n4) return;
  float4 f = ((const float4*)in)[i];
  ushort4 o;
  o.x = f2bf(f.x); o.y = f2bf(f.y); o.z = f2bf(f.z); o.w = f2bf(f.w);
  ((ushort4*)out)[i] = o;
}

// ---------------------------------------------------------------------------
// NT GEMM: C[M,N] = A[M,K] * B[N,K]^T   (both row-major bf16, fp32 accum)
// 128x128 tile, BK=32, 256 threads = 4 waves (2x2), each wave 64x64 via 4x4
// mfma_f32_16x16x32_bf16 tiles.  global_load_lds width-16 staging (m97).
// MODE 0: QKV  -> cols <2048 to qk (bf16), cols >=2048 to vt transposed
// MODE 1: scores -> *scale, causal mask, bf16, batched via blockIdx.z
// MODE 2: out  -> fp32 store, batched
// ---------------------------------------------------------------------------
template<int MODE>
__global__ __launch_bounds__(256) void gemm_nt(
    const u16* __restrict__ A, long long sA, int lda,
    const u16* __restrict__ B, long long sB, int ldb,
    void* __restrict__ Cp, long long sC, int ldc,
    int K, u16* __restrict__ vt, float scale, const int* __restrict__ causalp) {
  const int t = threadIdx.x;
  const int rowbase = blockIdx.x * 128;
  const int colbase = blockIdx.y * 128;
  const u16* Ab = A + (long long)blockIdx.z * sA;
  const u16* Bb = B + (long long)blockIdx.z * sB;

  __shared__ u16 As[4096];
  __shared__ u16 Bs[4096];

  const int lane = t & 63;
  const int wv = t >> 6;
  const int wr = wv >> 1;
  const int wc = wv & 1;
  const int quad = lane >> 4;
  const int lr = lane & 15;

  int causal = 1;
  bool skip = false;
  if (MODE == 1) {
    causal = causalp[0];
    skip = causal && (colbase > rowbase + 127);  // tile fully above diagonal
  }

  f32x4 acc[4][4];
  const f32x4 zero = {0.f, 0.f, 0.f, 0.f};
#pragma unroll
  for (int i = 0; i < 4; ++i)
#pragma unroll
    for (int j = 0; j < 4; ++j) acc[i][j] = zero;

  if (!skip) {
    const u16* ga  = Ab + (long long)(rowbase + (t >> 2)) * lda + (t & 3) * 8;
    const u16* ga2 = ga + (long long)64 * lda;
    const u16* gb  = Bb + (long long)(colbase + (t >> 2)) * ldb + (t & 3) * 8;
    const u16* gb2 = gb + (long long)64 * ldb;
    u16* la  = As + t * 8;
    u16* la2 = As + 2048 + t * 8;
    u16* lb  = Bs + t * 8;
    u16* lb2 = Bs + 2048 + t * 8;

    const int a_off = (wr * 64 + lr) * 32 + quad * 8;
    const int b_off = (wc * 64 + lr) * 32 + quad * 8;

    for (int k0 = 0; k0 < K; k0 += 32) {
      __syncthreads();               // prior frag reads done before overwrite
      llds16(ga + k0, la);
      llds16(ga2 + k0, la2);
      llds16(gb + k0, lb);
      llds16(gb2 + k0, lb2);
      __syncthreads();               // compiler drains vmcnt before barrier
      bf16x8 af[4], bfv[4];
#pragma unroll
      for (int tm = 0; tm < 4; ++tm)
        af[tm] = *(const bf16x8*)(As + a_off + tm * 512);
#pragma unroll
      for (int tn = 0; tn < 4; ++tn)
        bfv[tn] = *(const bf16x8*)(Bs + b_off + tn * 512);
#pragma unroll
      for (int tm = 0; tm < 4; ++tm)
#pragma unroll
        for (int tn = 0; tn < 4; ++tn)
          acc[tm][tn] = __builtin_amdgcn_mfma_f32_16x16x32_bf16(
              af[tm], bfv[tn], acc[tm][tn], 0, 0, 0);
    }
  }

  // ------------------------------ epilogue ------------------------------
  // C/D layout (m89/m91): col = lane&15, row = (lane>>4)*4 + reg
  if (MODE == 0 && colbase >= 2048) {
    // V block: write transposed to vt[b][e][s]; 4 regs = 4 consecutive s
#pragma unroll
    for (int tm = 0; tm < 4; ++tm) {
      int s0 = rowbase + wr * 64 + tm * 16 + quad * 4;
      int b = s0 >> 11;
      int sl = s0 & 2047;
#pragma unroll
      for (int tn = 0; tn < 4; ++tn) {
        int e = colbase - 2048 + wc * 64 + tn * 16 + lr;
        ushort4 o;
        o.x = f2bf(acc[tm][tn][0]);
        o.y = f2bf(acc[tm][tn][1]);
        o.z = f2bf(acc[tm][tn][2]);
        o.w = f2bf(acc[tm][tn][3]);
        *(ushort4*)(vt + ((long long)(b * 1024 + e)) * 2048 + sl) = o;
      }
    }
    return;
  }

#pragma unroll
  for (int tm = 0; tm < 4; ++tm) {
#pragma unroll
    for (int r = 0; r < 4; ++r) {
      int grow = rowbase + wr * 64 + tm * 16 + quad * 4 + r;
#pragma unroll
      for (int tn = 0; tn < 4; ++tn) {
        int gcol = colbase + wc * 64 + tn * 16 + lr;
        float val = acc[tm][tn][r];
        if (MODE == 0) {
          ((u16*)Cp)[(long long)grow * ldc + gcol] = f2bf(val);
        } else if (MODE == 1) {
          u16* C = (u16*)Cp + (long long)blockIdx.z * sC;
          u16 o = (causal && gcol > grow) ? (u16)0xFF80 : f2bf(val * scale);
          C[(long long)grow * ldc + gcol] = o;
        } else {
          float* C = (float*)Cp + (long long)blockIdx.z * sC;
          C[(long long)grow * ldc + gcol] = val;
        }
      }
    }
  }
}

// ---------------------------------------------------------------------------
// row softmax over 2048 cols, in place, bf16.  1 block / row, 8 elems/thread.
// masked entries are -inf (0xFF80) -> exp() = 0.
// ---------------------------------------------------------------------------
__global__ __launch_bounds__(256) void softmax_rows(u16* __restrict__ S) {
  const long long row = blockIdx.x;
  u16* rp = S + row * 2048;
  const int t = threadIdx.x;
  const int lane = t & 63;
  const int wv = t >> 6;
  __shared__ float red[4];

  union { uint4 u; u16 s[8]; } raw;
  raw.u = *(const uint4*)(rp + t * 8);
  float v[8];
#pragma unroll
  for (int i = 0; i < 8; ++i) v[i] = bf2f(raw.s[i]);

  float mx = v[0];
#pragma unroll
  for (int i = 1; i < 8; ++i) mx = fmaxf(mx, v[i]);
  for (int o = 32; o > 0; o >>= 1) mx = fmaxf(mx, __shfl_xor(mx, o, 64));
  if (lane == 0) red[wv] = mx;
  __syncthreads();
  mx = fmaxf(fmaxf(red[0], red[1]), fmaxf(red[2], red[3]));
  __syncthreads();

  float e[8];
  float sm = 0.f;
#pragma unroll
  for (int i = 0; i < 8; ++i) { e[i] = __expf(v[i] - mx); sm += e[i]; }
  for (int o = 32; o > 0; o >>= 1) sm += __shfl_xor(sm, o, 64);
  if (lane == 0) red[wv] = sm;
  __syncthreads();
  sm = red[0] + red[1] + red[2] + red[3];
  float inv = 1.0f / sm;

  union { uint4 u; u16 s[8]; } out;
#pragma unroll
  for (int i = 0; i < 8; ++i) out.s[i] = f2bf(e[i] * inv);
  *(uint4*)(rp + t * 8) = out.u;
}

// ---------------------------------------------------------------------------
extern "C" void kernel_launch(void* const* d_in, const int* in_sizes, int n_in,
                              void* d_out, int out_size, void* d_ws, size_t ws_size,
                              hipStream_t stream) {
  const float* x  = (const float*)d_in[0];
  const float* wq = (const float*)d_in[1];
  const float* wk = (const float*)d_in[2];
  const float* wv = (const float*)d_in[3];
  const int* causal = (const int*)d_in[4];
  float* out = (float*)d_out;

  // workspace layout (bytes):
  //   xb 0..16,777,216   wb ..23,068,672   qk ..56,623,104
  //   vt ..73,400,320    sb ..106,954,752   (~102 MB total)
  char* ws = (char*)d_ws;
  u16* xb = (u16*)(ws);               // [8192][1024] bf16 x
  u16* wb = (u16*)(ws + 16777216);    // [3072][1024] bf16 Wq|Wk|Wv
  u16* qk = (u16*)(ws + 23068672);    // [8192][2048] bf16 Q|K
  u16* vt = (u16*)(ws + 56623104);    // [4][1024][2048] bf16 V^T
  u16* sb = (u16*)(ws + 73400320);    // [4][2048][2048] bf16 scores/P

  cast_f32_bf16<<<8192, 256, 0, stream>>>(x, xb, 2097152);
  cast_f32_bf16<<<1024, 256, 0, stream>>>(wq, wb, 262144);
  cast_f32_bf16<<<1024, 256, 0, stream>>>(wk, wb + 1048576, 262144);
  cast_f32_bf16<<<1024, 256, 0, stream>>>(wv, wb + 2097152, 262144);

  // QKV: [8192 x 3072] = xb @ wb^T ; Q,K -> qk, V -> vt (transposed)
  gemm_nt<0><<<dim3(64, 24, 1), 256, 0, stream>>>(
      xb, 0, 1024, wb, 0, 1024, qk, 0, 2048, 1024, vt, 1.0f, causal);

  // scores per batch: S = (Q @ K^T) / 32, causal mask -> bf16
  gemm_nt<1><<<dim3(16, 16, 4), 256, 0, stream>>>(
      qk, 2048LL * 2048, 2048, qk + 1024, 2048LL * 2048, 2048,
      sb, 2048LL * 2048, 2048, 1024, nullptr, 0.03125f, causal);

  softmax_rows<<<8192, 256, 0, stream>>>(sb);

  // out per batch: [2048 x 1024] = P @ (V^T)^T  -> fp32
  gemm_nt<2><<<dim3(16, 8, 4), 256, 0, stream>>>(
      sb, 2048LL * 2048, 2048, vt, 1024LL * 2048, 2048,
      out, 2048LL * 1024, 1024, 2048, nullptr, 1.0f, causal);
}

// Round 2
// 297.286 us; speedup vs baseline: 1.0028x; 1.0028x over previous
//
#include <hip/hip_runtime.h>
#include <stdint.h>

typedef unsigned short u16;
typedef __attribute__((ext_vector_type(8))) __bf16 bf16x8;
typedef __attribute__((ext_vector_type(4))) float f32x4;

__device__ __forceinline__ u16 f2bf(float f) {
  unsigned u = __float_as_uint(f);
  u += 0x7FFF + ((u >> 16) & 1);   // RNE
  return (u16)(u >> 16);
}

__device__ __forceinline__ float bf2f(u16 h) {
  return __uint_as_float(((unsigned)h) << 16);
}

__device__ __forceinline__ void llds16(const u16* g, u16* l) {
  __builtin_amdgcn_global_load_lds(
      (const __attribute__((address_space(1))) void*)g,
      (__attribute__((address_space(3))) void*)l, 16, 0, 0);
}

// ---------------------------------------------------------------------------
// cast fp32 -> bf16, 4 elems/thread
// ---------------------------------------------------------------------------
__global__ __launch_bounds__(256) void cast_f32_bf16(
    const float* __restrict__ in, u16* __restrict__ out, int n4) {
  int i = blockIdx.x * 256 + threadIdx.x;
  if (i >= n4) return;
  float4 f = ((const float4*)in)[i];
  ushort4 o;
  o.x = f2bf(f.x); o.y = f2bf(f.y); o.z = f2bf(f.z); o.w = f2bf(f.w);
  ((ushort4*)out)[i] = o;
}

// ---------------------------------------------------------------------------
// NT GEMM: C[M,N] = A[M,K] * B[N,K]^T   (both row-major bf16, fp32 accum)
// 128x128 tile, BK=32, 256 threads = 4 waves (2x2), each wave 64x64 via 4x4
// mfma_f32_16x16x32_bf16 tiles.  global_load_lds width-16 staging (m97).
// LDS layout XOR-swizzled: row r's 16B chunk kc lives at linear chunk
// index r*4 + (kc ^ (r&3)) -> fragment reads are 2-way max (free, m136).
// MODE 0: QKV  -> cols <2048 to qk (bf16), cols >=2048 to vt transposed
// MODE 1: scores -> *scale, causal mask, bf16, batched via blockIdx.z
// MODE 2: out  -> fp32 store, batched
// ---------------------------------------------------------------------------
template<int MODE>
__global__ __launch_bounds__(256) void gemm_nt(
    const u16* __restrict__ A, long long sA, int lda,
    const u16* __restrict__ B, long long sB, int ldb,
    void* __restrict__ Cp, long long sC, int ldc,
    int K, u16* __restrict__ vt, float scale, const int* __restrict__ causalp) {
  const int t = threadIdx.x;
  const int rowbase = blockIdx.x * 128;
  const int colbase = blockIdx.y * 128;
  const u16* Ab = A + (long long)blockIdx.z * sA;
  const u16* Bb = B + (long long)blockIdx.z * sB;

  __shared__ u16 As[4096];
  __shared__ u16 Bs[4096];

  const int lane = t & 63;
  const int wv = t >> 6;
  const int wr = wv >> 1;
  const int wc = wv & 1;
  const int quad = lane >> 4;
  const int lr = lane & 15;

  int causal = 1;
  bool skip = false;
  if (MODE == 1) {
    causal = causalp[0];
    skip = causal && (colbase > rowbase + 127);  // tile fully above diagonal
  }

  f32x4 acc[4][4];
  const f32x4 zero = {0.f, 0.f, 0.f, 0.f};
#pragma unroll
  for (int i = 0; i < 4; ++i)
#pragma unroll
    for (int j = 0; j < 4; ++j) acc[i][j] = zero;

  if (!skip) {
    // staging: lane t fetches row (t>>2), K-chunk (t&3)^((t>>2)&3) -> LDS
    // lands at lane-linear offset (global_load_lds constraint), producing
    // the XOR-swizzled layout.
    const int kcs = (t & 3) ^ ((t >> 2) & 3);
    const u16* ga  = Ab + (long long)(rowbase + (t >> 2)) * lda + kcs * 8;
    const u16* ga2 = ga + (long long)64 * lda;
    const u16* gb  = Bb + (long long)(colbase + (t >> 2)) * ldb + kcs * 8;
    const u16* gb2 = gb + (long long)64 * ldb;
    u16* la  = As + t * 8;
    u16* la2 = As + 2048 + t * 8;
    u16* lb  = Bs + t * 8;
    u16* lb2 = Bs + 2048 + t * 8;

    // fragment read: row = wr*64 + tm*16 + lr (row&3 == lr&3), chunk quad
    const int a_off = (wr * 64 + lr) * 32 + ((quad ^ (lr & 3)) * 8);
    const int b_off = (wc * 64 + lr) * 32 + ((quad ^ (lr & 3)) * 8);

    for (int k0 = 0; k0 < K; k0 += 32) {
      __syncthreads();               // prior frag reads done before overwrite
      llds16(ga + k0, la);
      llds16(ga2 + k0, la2);
      llds16(gb + k0, lb);
      llds16(gb2 + k0, lb2);
      __syncthreads();               // compiler drains vmcnt before barrier
      bf16x8 af[4], bfv[4];
#pragma unroll
      for (int tm = 0; tm < 4; ++tm)
        af[tm] = *(const bf16x8*)(As + a_off + tm * 512);
#pragma unroll
      for (int tn = 0; tn < 4; ++tn)
        bfv[tn] = *(const bf16x8*)(Bs + b_off + tn * 512);
#pragma unroll
      for (int tm = 0; tm < 4; ++tm)
#pragma unroll
        for (int tn = 0; tn < 4; ++tn)
          acc[tm][tn] = __builtin_amdgcn_mfma_f32_16x16x32_bf16(
              af[tm], bfv[tn], acc[tm][tn], 0, 0, 0);
    }
  }

  // ------------------------------ epilogue ------------------------------
  // C/D layout (m89/m91): col = lane&15, row = (lane>>4)*4 + reg
  if (MODE == 0 && colbase >= 2048) {
    // V block: write transposed to vt[b][e][s]; 4 regs = 4 consecutive s
#pragma unroll
    for (int tm = 0; tm < 4; ++tm) {
      int s0 = rowbase + wr * 64 + tm * 16 + quad * 4;
      int b = s0 >> 11;
      int sl = s0 & 2047;
#pragma unroll
      for (int tn = 0; tn < 4; ++tn) {
        int e = colbase - 2048 + wc * 64 + tn * 16 + lr;
        ushort4 o;
        o.x = f2bf(acc[tm][tn][0]);
        o.y = f2bf(acc[tm][tn][1]);
        o.z = f2bf(acc[tm][tn][2]);
        o.w = f2bf(acc[tm][tn][3]);
        *(ushort4*)(vt + ((long long)(b * 1024 + e)) * 2048 + sl) = o;
      }
    }
    return;
  }

#pragma unroll
  for (int tm = 0; tm < 4; ++tm) {
#pragma unroll
    for (int r = 0; r < 4; ++r) {
      int grow = rowbase + wr * 64 + tm * 16 + quad * 4 + r;
#pragma unroll
      for (int tn = 0; tn < 4; ++tn) {
        int gcol = colbase + wc * 64 + tn * 16 + lr;
        float val = acc[tm][tn][r];
        if (MODE == 0) {
          ((u16*)Cp)[(long long)grow * ldc + gcol] = f2bf(val);
        } else if (MODE == 1) {
          u16* C = (u16*)Cp + (long long)blockIdx.z * sC;
          u16 o = (causal && gcol > grow) ? (u16)0xFF80 : f2bf(val * scale);
          C[(long long)grow * ldc + gcol] = o;
        } else {
          float* C = (float*)Cp + (long long)blockIdx.z * sC;
          C[(long long)grow * ldc + gcol] = val;
        }
      }
    }
  }
}

// ---------------------------------------------------------------------------
// row softmax over 2048 cols, in place, bf16.  1 block / row, 8 elems/thread.
// masked entries are -inf (0xFF80) -> exp() = 0.
// ---------------------------------------------------------------------------
__global__ __launch_bounds__(256) void softmax_rows(u16* __restrict__ S) {
  const long long row = blockIdx.x;
  u16* rp = S + row * 2048;
  const int t = threadIdx.x;
  const int lane = t & 63;
  const int wv = t >> 6;
  __shared__ float red[4];

  union { uint4 u; u16 s[8]; } raw;
  raw.u = *(const uint4*)(rp + t * 8);
  float v[8];
#pragma unroll
  for (int i = 0; i < 8; ++i) v[i] = bf2f(raw.s[i]);

  float mx = v[0];
#pragma unroll
  for (int i = 1; i < 8; ++i) mx = fmaxf(mx, v[i]);
  for (int o = 32; o > 0; o >>= 1) mx = fmaxf(mx, __shfl_xor(mx, o, 64));
  if (lane == 0) red[wv] = mx;
  __syncthreads();
  mx = fmaxf(fmaxf(red[0], red[1]), fmaxf(red[2], red[3]));
  __syncthreads();

  float e[8];
  float sm = 0.f;
#pragma unroll
  for (int i = 0; i < 8; ++i) { e[i] = __expf(v[i] - mx); sm += e[i]; }
  for (int o = 32; o > 0; o >>= 1) sm += __shfl_xor(sm, o, 64);
  if (lane == 0) red[wv] = sm;
  __syncthreads();
  sm = red[0] + red[1] + red[2] + red[3];
  float inv = 1.0f / sm;

  union { uint4 u; u16 s[8]; } out;
#pragma unroll
  for (int i = 0; i < 8; ++i) out.s[i] = f2bf(e[i] * inv);
  *(uint4*)(rp + t * 8) = out.u;
}

// ---------------------------------------------------------------------------
extern "C" void kernel_launch(void* const* d_in, const int* in_sizes, int n_in,
                              void* d_out, int out_size, void* d_ws, size_t ws_size,
                              hipStream_t stream) {
  const float* x  = (const float*)d_in[0];
  const float* wq = (const float*)d_in[1];
  const float* wk = (const float*)d_in[2];
  const float* wv = (const float*)d_in[3];
  const int* causal = (const int*)d_in[4];
  float* out = (float*)d_out;

  // workspace layout (bytes):
  //   xb 0..16,777,216   wb ..23,068,672   qk ..56,623,104
  //   vt ..73,400,320    sb ..106,954,752   (~102 MB total)
  char* ws = (char*)d_ws;
  u16* xb = (u16*)(ws);               // [8192][1024] bf16 x
  u16* wb = (u16*)(ws + 16777216);    // [3072][1024] bf16 Wq|Wk|Wv
  u16* qk = (u16*)(ws + 23068672);    // [8192][2048] bf16 Q|K
  u16* vt = (u16*)(ws + 56623104);    // [4][1024][2048] bf16 V^T
  u16* sb = (u16*)(ws + 73400320);    // [4][2048][2048] bf16 scores/P

  cast_f32_bf16<<<8192, 256, 0, stream>>>(x, xb, 2097152);
  cast_f32_bf16<<<1024, 256, 0, stream>>>(wq, wb, 262144);
  cast_f32_bf16<<<1024, 256, 0, stream>>>(wk, wb + 1048576, 262144);
  cast_f32_bf16<<<1024, 256, 0, stream>>>(wv, wb + 2097152, 262144);

  // QKV: [8192 x 3072] = xb @ wb^T ; Q,K -> qk, V -> vt (transposed)
  gemm_nt<0><<<dim3(64, 24, 1), 256, 0, stream>>>(
      xb, 0, 1024, wb, 0, 1024, qk, 0, 2048, 1024, vt, 1.0f, causal);

  // scores per batch: S = (Q @ K^T) / 32, causal mask -> bf16
  gemm_nt<1><<<dim3(16, 16, 4), 256, 0, stream>>>(
      qk, 2048LL * 2048, 2048, qk + 1024, 2048LL * 2048, 2048,
      sb, 2048LL * 2048, 2048, 1024, nullptr, 0.03125f, causal);

  softmax_rows<<<8192, 256, 0, stream>>>(sb);

  // out per batch: [2048 x 1024] = P @ (V^T)^T  -> fp32
  gemm_nt<2><<<dim3(16, 8, 4), 256, 0, stream>>>(
      sb, 2048LL * 2048, 2048, vt, 1024LL * 2048, 2048,
      out, 2048LL * 1024, 1024, 2048, nullptr, 1.0f, causal);
}

// Round 3
// 269.946 us; speedup vs baseline: 1.1044x; 1.1013x over previous
//
#include <hip/hip_runtime.h>
#include <stdint.h>

typedef unsigned short u16;
typedef __attribute__((ext_vector_type(8))) __bf16 bf16x8;
typedef __attribute__((ext_vector_type(4))) float f32x4;

__device__ __forceinline__ u16 f2bf(float f) {
  unsigned u = __float_as_uint(f);
  u += 0x7FFF + ((u >> 16) & 1);   // RNE
  return (u16)(u >> 16);
}

__device__ __forceinline__ float bf2f(u16 h) {
  return __uint_as_float(((unsigned)h) << 16);
}

__device__ __forceinline__ void llds16(const u16* g, u16* l) {
  __builtin_amdgcn_global_load_lds(
      (const __attribute__((address_space(1))) void*)g,
      (__attribute__((address_space(3))) void*)l, 16, 0, 0);
}

// ---------------------------------------------------------------------------
// fused cast fp32 -> bf16 for x | wq | wk | wv, 4 elems/thread, one launch
// ---------------------------------------------------------------------------
__global__ __launch_bounds__(256) void cast_all(
    const float* __restrict__ x, const float* __restrict__ wq,
    const float* __restrict__ wk, const float* __restrict__ wv,
    u16* __restrict__ xb, u16* __restrict__ wb) {
  int i = blockIdx.x * 256 + threadIdx.x;
  const float* src; u16* dst; int off;
  if (i < 2097152)      { src = x;  dst = xb;            off = i; }
  else if (i < 2359296) { src = wq; dst = wb;            off = i - 2097152; }
  else if (i < 2621440) { src = wk; dst = wb + 1048576;  off = i - 2359296; }
  else                  { src = wv; dst = wb + 2097152;  off = i - 2621440; }
  float4 f = ((const float4*)src)[off];
  ushort4 o;
  o.x = f2bf(f.x); o.y = f2bf(f.y); o.z = f2bf(f.z); o.w = f2bf(f.w);
  ((ushort4*)dst)[off] = o;
}

// ---------------------------------------------------------------------------
// NT GEMM: C[M,N] = A[M,K] * B[N,K]^T   (row-major bf16, fp32 accum)
// 128x128 tile, BK=32, 256 threads = 4 waves (2x2), each wave 64x64 via 4x4
// mfma_f32_16x16x32_bf16.  global_load_lds width-16 staging (m97).
// NOTE: SQ_LDS_BANK_CONFLICT ~8/load is the DMA's inherent LDS-write
// serialization (16B/lane x 64 lanes over 32 banks) — not actionable.
// MODE 0: QKV  -> cols <2048 to qk (bf16), cols >=2048 to vt transposed
// MODE 1: scores -> triangular-first block decode, *scale, causal mask, bf16
// MODE 2: PV -> fp32 store, causal K-truncation (P lower-triangular),
//         longest-row-tiles-first dispatch order
// ---------------------------------------------------------------------------
template<int MODE>
__global__ __launch_bounds__(256) void gemm_nt(
    const u16* __restrict__ A, long long sA, int lda,
    const u16* __restrict__ B, long long sB, int ldb,
    void* __restrict__ Cp, long long sC, int ldc,
    int K, u16* __restrict__ vt, float scale, const int* __restrict__ causalp) {
  const int t = threadIdx.x;
  const int causal = (MODE == 0) ? 1 : causalp[0];

  int rt = blockIdx.x, ct = blockIdx.y;
  if (MODE == 1) {
    // decode blockIdx.x (0..255) -> (rt, ct); first 136 = lower triangle
    // (dispatch first), last 120 = strict upper (skip instantly if causal)
    int x = blockIdx.x;
    if (x < 136) {
      int r = (int)((sqrtf(8.0f * x + 1.0f) - 1.0f) * 0.5f);
      while ((r + 1) * (r + 2) / 2 <= x) ++r;
      while (r * (r + 1) / 2 > x) --r;
      rt = r; ct = x - r * (r + 1) / 2;
    } else {
      int y = x - 136;
      int r = (int)((sqrtf(8.0f * y + 1.0f) - 1.0f) * 0.5f);
      while ((r + 1) * (r + 2) / 2 <= y) ++r;
      while (r * (r + 1) / 2 > y) --r;
      int c = y - r * (r + 1) / 2;
      rt = c; ct = r + 1;                   // strict upper tile
      if (causal) return;                   // never needed when causal
    }
  }
  if (MODE == 2) rt = 15 - blockIdx.x;      // longest K first

  const int rowbase = rt * 128;
  const int colbase = ct * 128;
  const u16* Ab = A + (long long)blockIdx.z * sA;
  const u16* Bb = B + (long long)blockIdx.z * sB;

  // causal PV: P[i,k]=0 for k>i -> only need k < rowbase+128
  int Keff = K;
  if (MODE == 2 && causal) Keff = min(K, rowbase + 128);

  __shared__ u16 As[4096];
  __shared__ u16 Bs[4096];

  const int lane = t & 63;
  const int wv = t >> 6;
  const int wr = wv >> 1;
  const int wc = wv & 1;
  const int quad = lane >> 4;
  const int lr = lane & 15;

  f32x4 acc[4][4];
  const f32x4 zero = {0.f, 0.f, 0.f, 0.f};
#pragma unroll
  for (int i = 0; i < 4; ++i)
#pragma unroll
    for (int j = 0; j < 4; ++j) acc[i][j] = zero;

  {
    const u16* ga  = Ab + (long long)(rowbase + (t >> 2)) * lda + (t & 3) * 8;
    const u16* ga2 = ga + (long long)64 * lda;
    const u16* gb  = Bb + (long long)(colbase + (t >> 2)) * ldb + (t & 3) * 8;
    const u16* gb2 = gb + (long long)64 * ldb;
    u16* la  = As + t * 8;
    u16* la2 = As + 2048 + t * 8;
    u16* lb  = Bs + t * 8;
    u16* lb2 = Bs + 2048 + t * 8;

    const int a_off = (wr * 64 + lr) * 32 + quad * 8;
    const int b_off = (wc * 64 + lr) * 32 + quad * 8;

    for (int k0 = 0; k0 < Keff; k0 += 32) {
      __syncthreads();               // prior frag reads done before overwrite
      llds16(ga + k0, la);
      llds16(ga2 + k0, la2);
      llds16(gb + k0, lb);
      llds16(gb2 + k0, lb2);
      __syncthreads();               // compiler drains vmcnt before barrier
      bf16x8 af[4], bfv[4];
#pragma unroll
      for (int tm = 0; tm < 4; ++tm)
        af[tm] = *(const bf16x8*)(As + a_off + tm * 512);
#pragma unroll
      for (int tn = 0; tn < 4; ++tn)
        bfv[tn] = *(const bf16x8*)(Bs + b_off + tn * 512);
#pragma unroll
      for (int tm = 0; tm < 4; ++tm)
#pragma unroll
        for (int tn = 0; tn < 4; ++tn)
          acc[tm][tn] = __builtin_amdgcn_mfma_f32_16x16x32_bf16(
              af[tm], bfv[tn], acc[tm][tn], 0, 0, 0);
    }
  }

  // ------------------------------ epilogue ------------------------------
  // C/D layout (m89/m91): col = lane&15, row = (lane>>4)*4 + reg
  if (MODE == 0 && colbase >= 2048) {
    // V block: write transposed to vt[b][e][s]; 4 regs = 4 consecutive s
#pragma unroll
    for (int tm = 0; tm < 4; ++tm) {
      int s0 = rowbase + wr * 64 + tm * 16 + quad * 4;
      int b = s0 >> 11;
      int sl = s0 & 2047;
#pragma unroll
      for (int tn = 0; tn < 4; ++tn) {
        int e = colbase - 2048 + wc * 64 + tn * 16 + lr;
        ushort4 o;
        o.x = f2bf(acc[tm][tn][0]);
        o.y = f2bf(acc[tm][tn][1]);
        o.z = f2bf(acc[tm][tn][2]);
        o.w = f2bf(acc[tm][tn][3]);
        *(ushort4*)(vt + ((long long)(b * 1024 + e)) * 2048 + sl) = o;
      }
    }
    return;
  }

#pragma unroll
  for (int tm = 0; tm < 4; ++tm) {
#pragma unroll
    for (int r = 0; r < 4; ++r) {
      int grow = rowbase + wr * 64 + tm * 16 + quad * 4 + r;
#pragma unroll
      for (int tn = 0; tn < 4; ++tn) {
        int gcol = colbase + wc * 64 + tn * 16 + lr;
        float val = acc[tm][tn][r];
        if (MODE == 0) {
          ((u16*)Cp)[(long long)grow * ldc + gcol] = f2bf(val);
        } else if (MODE == 1) {
          u16* C = (u16*)Cp + (long long)blockIdx.z * sC;
          u16 o = (causal && gcol > grow) ? (u16)0xFF80 : f2bf(val * scale);
          C[(long long)grow * ldc + gcol] = o;
        } else {
          float* C = (float*)Cp + (long long)blockIdx.z * sC;
          C[(long long)grow * ldc + gcol] = val;
        }
      }
    }
  }
}

// ---------------------------------------------------------------------------
// row softmax over cols [0, colmax), in place, bf16. 1 block/row, 8/thread.
// When causal, cols >= colmax = (row|127)+1 are NEVER written by the
// triangular scores GEMM (poison!) and never read by the K-truncated PV —
// they are neither read nor written here.  Masked entries inside the
// diagonal tile are -inf -> exp()=0 (PV does read those).
// ---------------------------------------------------------------------------
__global__ __launch_bounds__(256) void softmax_rows(
    u16* __restrict__ S, const int* __restrict__ causalp) {
  const long long row = blockIdx.x;
  const int rloc = blockIdx.x & 2047;
  const int colmax = causalp[0] ? ((rloc | 127) + 1) : 2048;
  u16* rp = S + row * 2048;
  const int t = threadIdx.x;
  const int lane = t & 63;
  const int wv = t >> 6;
  const bool act = (t * 8) < colmax;
  __shared__ float red[4];

  float v[8];
#pragma unroll
  for (int i = 0; i < 8; ++i) v[i] = -__builtin_inff();
  if (act) {
    union { uint4 u; u16 s[8]; } raw;
    raw.u = *(const uint4*)(rp + t * 8);
#pragma unroll
    for (int i = 0; i < 8; ++i) v[i] = bf2f(raw.s[i]);
  }

  float mx = v[0];
#pragma unroll
  for (int i = 1; i < 8; ++i) mx = fmaxf(mx, v[i]);
  for (int o = 32; o > 0; o >>= 1) mx = fmaxf(mx, __shfl_xor(mx, o, 64));
  if (lane == 0) red[wv] = mx;
  __syncthreads();
  mx = fmaxf(fmaxf(red[0], red[1]), fmaxf(red[2], red[3]));
  __syncthreads();

  float e[8];
  float sm = 0.f;
#pragma unroll
  for (int i = 0; i < 8; ++i) { e[i] = __expf(v[i] - mx); sm += e[i]; }
  for (int o = 32; o > 0; o >>= 1) sm += __shfl_xor(sm, o, 64);
  if (lane == 0) red[wv] = sm;
  __syncthreads();
  sm = red[0] + red[1] + red[2] + red[3];
  float inv = 1.0f / sm;

  if (act) {
    union { uint4 u; u16 s[8]; } out;
#pragma unroll
    for (int i = 0; i < 8; ++i) out.s[i] = f2bf(e[i] * inv);
    *(uint4*)(rp + t * 8) = out.u;
  }
}

// ---------------------------------------------------------------------------
extern "C" void kernel_launch(void* const* d_in, const int* in_sizes, int n_in,
                              void* d_out, int out_size, void* d_ws, size_t ws_size,
                              hipStream_t stream) {
  const float* x  = (const float*)d_in[0];
  const float* wq = (const float*)d_in[1];
  const float* wk = (const float*)d_in[2];
  const float* wv = (const float*)d_in[3];
  const int* causal = (const int*)d_in[4];
  float* out = (float*)d_out;

  // workspace layout (bytes):
  //   xb 0..16,777,216   wb ..23,068,672   qk ..56,623,104
  //   vt ..73,400,320    sb ..106,954,752   (~102 MB total)
  char* ws = (char*)d_ws;
  u16* xb = (u16*)(ws);               // [8192][1024] bf16 x
  u16* wb = (u16*)(ws + 16777216);    // [3072][1024] bf16 Wq|Wk|Wv
  u16* qk = (u16*)(ws + 23068672);    // [8192][2048] bf16 Q|K
  u16* vt = (u16*)(ws + 56623104);    // [4][1024][2048] bf16 V^T
  u16* sb = (u16*)(ws + 73400320);    // [4][2048][2048] bf16 scores/P

  // casts: 2883584 float4 total (x, wq, wk, wv) in one launch
  cast_all<<<11264, 256, 0, stream>>>(x, wq, wk, wv, xb, wb);

  // QKV: [8192 x 3072] = xb @ wb^T ; Q,K -> qk, V -> vt (transposed)
  gemm_nt<0><<<dim3(64, 24, 1), 256, 0, stream>>>(
      xb, 0, 1024, wb, 0, 1024, qk, 0, 2048, 1024, vt, 1.0f, causal);

  // scores per batch: S = (Q @ K^T) / 32, causal mask -> bf16
  // triangular-first decode inside the kernel; grid.x=256 covers all tiles
  gemm_nt<1><<<dim3(256, 1, 4), 256, 0, stream>>>(
      qk, 2048LL * 2048, 2048, qk + 1024, 2048LL * 2048, 2048,
      sb, 2048LL * 2048, 2048, 1024, nullptr, 0.03125f, causal);

  softmax_rows<<<8192, 256, 0, stream>>>(sb, causal);

  // out per batch: [2048 x 1024] = P @ (V^T)^T -> fp32, K truncated by causal
  gemm_nt<2><<<dim3(16, 8, 4), 256, 0, stream>>>(
      sb, 2048LL * 2048, 2048, vt, 1024LL * 2048, 2048,
      out, 2048LL * 1024, 1024, 2048, nullptr, 1.0f, causal);
}